// Round 13
// baseline (115.871 us; speedup 1.0000x reference)
//
#include <hip/hip_runtime.h>
#include <math.h>

#define B_TOT   1024
#define L_SEQ   200
#define DIM     64
#define VOCAB   100001
#define NEG_BIG (-1e15f)
#define SEQ_ST16 66                     // bf16 row stride: 132 B -> 2-way (free) on both write & read
#define LOG2E   1.4426950408889634f

typedef __bf16 bf16x8 __attribute__((ext_vector_type(8)));
typedef float  f32x4  __attribute__((ext_vector_type(4)));

// raw v_exp_f32 (exp2): inputs are bounded here, denormal guard unneeded
static __device__ __forceinline__ float fast_exp2(float x) {
    return __builtin_amdgcn_exp2f(x);
}

static __device__ __forceinline__ bf16x8 cvt_bf16x8(const float4 a, const float4 b) {
    bf16x8 o;
    o[0] = (__bf16)a.x; o[1] = (__bf16)a.y; o[2] = (__bf16)a.z; o[3] = (__bf16)a.w;
    o[4] = (__bf16)b.x; o[5] = (__bf16)b.y; o[6] = (__bf16)b.z; o[7] = (__bf16)b.w;
    return o;
}

// ---------------------------------------------------------------------------
// Kernel A: attention pooling (no convert tail — logits reads f32 E directly).
// Phase 1: thread l gathers its E row ONCE, computes seq[l][:] = 8*E+pos,
//          stores bf16 to LDS, computes sim[l].
// Phase 2: block softmax.  Phase 3: LDS column sum, L split across waves.
// ---------------------------------------------------------------------------
__global__ __launch_bounds__(256) void pool_kernel(
    const int*   __restrict__ log_seqs,
    const float* __restrict__ item_emb,
    const float* __restrict__ attn_key,
    const float* __restrict__ pos_emb,
    float*       __restrict__ Q,
    __bf16*      __restrict__ Qb)
{
    const int b    = blockIdx.x;
    const int t    = threadIdx.x;
    const int wave = t >> 6;
    const int lane = t & 63;

    __shared__ unsigned short s_seq16[L_SEQ][SEQ_ST16];  // 26,400 B
    __shared__ float s_attn[L_SEQ];
    __shared__ float s_red[4];
    __shared__ float s_q[4][DIM];

    // ---- phase 1: seq row -> LDS (bf16), sim[l] ---------------------------
    float sim = -INFINITY;
    if (t < L_SEQ) {
        const int id = log_seqs[(long)b * L_SEQ + t];
        if (id == 0) {
            sim = NEG_BIG;
            const ushort2 z = make_ushort2(0, 0);
            #pragma unroll
            for (int i = 0; i < DIM / 2; ++i)
                *(ushort2*)&s_seq16[t][2 * i] = z;
        } else {
            float acc = 0.f;
            const float4* e4 = (const float4*)(item_emb + (long)id * DIM);
            const float4* p4 = (const float4*)(pos_emb + t * DIM);
            #pragma unroll
            for (int i = 0; i < DIM / 4; ++i) {
                const float4 e = e4[i];
                const float4 p = p4[i];
                float4 f;
                f.x = fmaf(8.f, e.x, p.x);
                f.y = fmaf(8.f, e.y, p.y);
                f.z = fmaf(8.f, e.z, p.z);
                f.w = fmaf(8.f, e.w, p.w);
                const __bf16 h0 = (__bf16)f.x, h1 = (__bf16)f.y;
                const __bf16 h2 = (__bf16)f.z, h3 = (__bf16)f.w;
                ushort2 u0, u1;
                u0.x = __builtin_bit_cast(unsigned short, h0);
                u0.y = __builtin_bit_cast(unsigned short, h1);
                u1.x = __builtin_bit_cast(unsigned short, h2);
                u1.y = __builtin_bit_cast(unsigned short, h3);
                *(ushort2*)&s_seq16[t][4 * i]     = u0;
                *(ushort2*)&s_seq16[t][4 * i + 2] = u1;
                // attn_key reads are thread-uniform -> scalar loads
                acc += f.x * attn_key[4*i+0] + f.y * attn_key[4*i+1]
                     + f.z * attn_key[4*i+2] + f.w * attn_key[4*i+3];
            }
            sim = acc;
        }
    }

    // ---- phase 2: block softmax over l -------------------------------------
    float m = sim;
    #pragma unroll
    for (int off = 32; off > 0; off >>= 1) m = fmaxf(m, __shfl_xor(m, off));
    if (lane == 0) s_red[wave] = m;
    __syncthreads();
    m = fmaxf(fmaxf(s_red[0], s_red[1]), fmaxf(s_red[2], s_red[3]));
    __syncthreads();                             // all waves read s_red

    float p = (t < L_SEQ) ? __expf(sim - m) : 0.f;
    if (t < L_SEQ) s_attn[t] = p;
    float ls = p;
    #pragma unroll
    for (int off = 32; off > 0; off >>= 1) ls += __shfl_xor(ls, off);
    if (lane == 0) s_red[wave] = ls;
    __syncthreads();
    const float inv = 1.0f / (s_red[0] + s_red[1] + s_red[2] + s_red[3]);

    // ---- phase 3: Q accumulation from LDS, L split across waves ------------
    float q = 0.f;
    const int l0 = wave * (L_SEQ / 4);
    #pragma unroll 2
    for (int l = l0; l < l0 + (L_SEQ / 4); ++l) {
        const unsigned int ui = (unsigned int)s_seq16[l][lane] << 16;
        q = fmaf(s_attn[l], __builtin_bit_cast(float, ui), q);
    }
    s_q[wave][lane] = q;
    __syncthreads();

    if (t < DIM) {
        const float qq = (s_q[0][t] + s_q[1][t] + s_q[2][t] + s_q[3][t]) * inv;
        Q[b * DIM + t]  = qq;
        Qb[b * DIM + t] = (__bf16)(qq * LOG2E);  // exp2-domain for logits kernel
    }
}

// ---------------------------------------------------------------------------
// Kernel B: bf16 MFMA logits GEMM + exp2-sum partials.
// R8 structure (best measured): NC=128, 128 rows/block = 8 b-tiles, waves
// split vtiles mod 4, each B-load feeds 8 MFMAs.  NEW: reads item_emb f32
// directly (no pre-converted Eb) with in-register bf16 conversion at use —
// kills the convert pass; E crosses L3 once (25.6 MB), chunk re-reads are
// XCD-local L2 hits.  __launch_bounds__(256,3) caps regs ~170 to guarantee
// >=3 waves/SIMD (live set ~150, no spill).
// Clamped rows keep all loads in-bounds; tail vtile masks valid?:0.
// XCD-aware decode: XCD k owns chunks == k (mod 8).
// ---------------------------------------------------------------------------
#define NC        128                   // vocab chunks
#define NBG       8                     // batch groups (1024/128)
#define VT_TOTAL  6251                  // ceil(100001/16)
#define VT_FULL   6250
#define VT_PER    49                    // ceil(VT_TOTAL/NC)

__global__ __launch_bounds__(256, 3) void logits_mfma(
    const float*  __restrict__ E,       // [VOCAB][64] f32
    const __bf16* __restrict__ Qb,      // [1024][64], exp2-domain
    float*        __restrict__ partials) // [NC][1024]
{
    const int bid   = blockIdx.x;                 // 0..1023
    const int xcd   = bid & 7;          // HW round-robins blockIdx across XCDs
    const int idx   = bid >> 3;         // 0..127 within this XCD
    const int chunk = xcd + 8 * (idx >> 3);       // chunks == xcd (mod 8)
    const int bg    = idx & 7;
    const int wave  = threadIdx.x >> 6;
    const int lane  = threadIdx.x & 63;
    const int r16   = lane & 15;
    const int hi    = lane >> 4;

    __shared__ float s_part[4][128];

    bf16x8 a[8][2];
    #pragma unroll
    for (int t = 0; t < 8; ++t)
        #pragma unroll
        for (int s = 0; s < 2; ++s)
            a[t][s] = *(const bf16x8*)(Qb + ((bg*128 + t*16 + r16) * DIM) + s*32 + hi*8);

    const int vt0    = chunk * VT_PER;
    const int vt_end = min(vt0 + VT_PER, VT_TOTAL);
    int vt = vt0 + wave;

    float ssum[8][4];
    #pragma unroll
    for (int t = 0; t < 8; ++t)
        #pragma unroll
        for (int r = 0; r < 4; ++r) ssum[t][r] = 0.f;

    // f32 B-fragment load, row-clamped (always in-bounds)
    #define LOADB(dst, vti) do {                                              \
        const int _row = min((vti) * 16 + r16, VOCAB - 1);                    \
        const float* _p = E + (size_t)_row * DIM + hi * 8;                    \
        dst[0] = ((const float4*)_p)[0];                                      \
        dst[1] = ((const float4*)_p)[1];                                      \
        dst[2] = ((const float4*)(_p + 32))[0];                               \
        dst[3] = ((const float4*)(_p + 32))[1];                               \
    } while (0)

    #define DO_TILE(c0, c1, v) do {                                           \
        if ((v) < VT_FULL) {                                                  \
            _Pragma("unroll")                                                 \
            for (int t = 0; t < 8; ++t) {                                     \
                f32x4 acc = {0.f, 0.f, 0.f, 0.f};                             \
                acc = __builtin_amdgcn_mfma_f32_16x16x32_bf16(a[t][0], c0, acc, 0, 0, 0); \
                acc = __builtin_amdgcn_mfma_f32_16x16x32_bf16(a[t][1], c1, acc, 0, 0, 0); \
                _Pragma("unroll")                                             \
                for (int r = 0; r < 4; ++r) ssum[t][r] += fast_exp2(acc[r]);  \
            }                                                                 \
        } else {                                                              \
            const bool valid = ((v) * 16 + r16) < VOCAB;                      \
            _Pragma("unroll")                                                 \
            for (int t = 0; t < 8; ++t) {                                     \
                f32x4 acc = {0.f, 0.f, 0.f, 0.f};                             \
                acc = __builtin_amdgcn_mfma_f32_16x16x32_bf16(a[t][0], c0, acc, 0, 0, 0); \
                acc = __builtin_amdgcn_mfma_f32_16x16x32_bf16(a[t][1], c1, acc, 0, 0, 0); \
                _Pragma("unroll")                                             \
                for (int r = 0; r < 4; ++r) ssum[t][r] += valid ? fast_exp2(acc[r]) : 0.f; \
            }                                                                 \
        }                                                                     \
    } while (0)

    float4 bA[4], bB[4];
    LOADB(bA, vt);
    LOADB(bB, vt + 4);

    while (vt < vt_end) {
        float4 cA[4], cB[4];
        #pragma unroll
        for (int i = 0; i < 4; ++i) { cA[i] = bA[i]; cB[i] = bB[i]; }
        const int v0 = vt, v1 = vt + 4;
        vt += 8;
        LOADB(bA, vt);
        LOADB(bB, vt + 4);

        {
            const bf16x8 c0 = cvt_bf16x8(cA[0], cA[1]);
            const bf16x8 c1 = cvt_bf16x8(cA[2], cA[3]);
            DO_TILE(c0, c1, v0);
        }
        if (v1 < vt_end) {
            const bf16x8 c0 = cvt_bf16x8(cB[0], cB[1]);
            const bf16x8 c1 = cvt_bf16x8(cB[2], cB[3]);
            DO_TILE(c0, c1, v1);
        }
    }
    #undef DO_TILE
    #undef LOADB

    // reduce exp-sums across the 16 vocab cols (lanes differing in bits 0..3)
    #pragma unroll
    for (int t = 0; t < 8; ++t)
        #pragma unroll
        for (int r = 0; r < 4; ++r) {
            float v = ssum[t][r];
            v += __shfl_xor(v, 1);
            v += __shfl_xor(v, 2);
            v += __shfl_xor(v, 4);
            v += __shfl_xor(v, 8);
            ssum[t][r] = v;
        }

    // cross-wave reduce in LDS -> one value per row per block
    if (r16 == 0) {
        #pragma unroll
        for (int t = 0; t < 8; ++t)
            #pragma unroll
            for (int r = 0; r < 4; ++r)
                s_part[wave][t * 16 + hi * 4 + r] = ssum[t][r];
    }
    __syncthreads();

    if (threadIdx.x < 128) {
        const int i = threadIdx.x;
        const float v = s_part[0][i] + s_part[1][i] + s_part[2][i] + s_part[3][i];
        partials[(size_t)chunk * B_TOT + bg * 128 + i] = v;
    }
}

// ---------------------------------------------------------------------------
// Kernel C: reduce partials, exact fp32 pred logit, emit prob.
// ---------------------------------------------------------------------------
__global__ __launch_bounds__(256) void finalize_kernel(
    const float* __restrict__ Q,
    const float* __restrict__ item_emb,
    const int*   __restrict__ pred,
    const float* __restrict__ partials,
    float*       __restrict__ out)
{
    const int b = blockIdx.x * 256 + threadIdx.x;

    float S = 0.f;
    for (int c = 0; c < NC; ++c)
        S += partials[(size_t)c * B_TOT + b];

    const int pv = pred[b];
    float acc = 0.f;
    const float4* e4 = (const float4*)(item_emb + (long)pv * DIM);
    const float4* q4 = (const float4*)(Q + b * DIM);
    #pragma unroll
    for (int i = 0; i < DIM / 4; ++i) {
        const float4 e = e4[i];
        const float4 q = q4[i];
        acc += e.x*q.x + e.y*q.y + e.z*q.z + e.w*q.w;
    }
    out[b] = __expf(acc) / S;
}

// ---------------------------------------------------------------------------
extern "C" void kernel_launch(void* const* d_in, const int* in_sizes, int n_in,
                              void* d_out, int out_size, void* d_ws, size_t ws_size,
                              hipStream_t stream)
{
    const int*   log_seqs = (const int*)  d_in[0];
    const int*   pred     = (const int*)  d_in[1];
    const float* item_emb = (const float*)d_in[2];
    const float* attn_key = (const float*)d_in[3];
    const float* pos_emb  = (const float*)d_in[4];
    float*       out      = (float*)d_out;

    char* ws = (char*)d_ws;
    __bf16* Qb       = (__bf16*)ws;                                     // 131,072 B
    float*  Qf       = (float*) (ws + (size_t)B_TOT * DIM * 2);
    float*  partials = (float*) ((char*)Qf + (size_t)B_TOT * DIM * 4);  // [128][1024] f32

    pool_kernel<<<B_TOT, 256, 0, stream>>>(log_seqs, item_emb, attn_key, pos_emb, Qf, Qb);
    logits_mfma<<<NBG * NC, 256, 0, stream>>>(item_emb, Qb, partials);
    finalize_kernel<<<B_TOT / 256, 256, 0, stream>>>(Qf, item_emb, pred, partials, out);
}

// Round 14
// 70.291 us; speedup vs baseline: 1.6485x; 1.6485x over previous
//
#include <hip/hip_runtime.h>
#include <math.h>

#define B_TOT   1024
#define L_SEQ   200
#define DIM     64
#define VOCAB   100001
#define NEG_BIG (-1e15f)
#define SEQ_ST16 66                     // bf16 row stride: 132 B -> 2-way (free) on both write & read
#define LOG2E   1.4426950408889634f
#define EB_SLACK_ROWS 512               // prefetch overrun slack (values never used)

typedef __bf16 bf16x8 __attribute__((ext_vector_type(8)));
typedef float  f32x4  __attribute__((ext_vector_type(4)));

#define GLB_AS __attribute__((address_space(1)))
#define LDS_AS __attribute__((address_space(3)))

// raw v_exp_f32 (exp2): inputs are bounded here, denormal guard unneeded
static __device__ __forceinline__ float fast_exp2(float x) {
    return __builtin_amdgcn_exp2f(x);
}

// ---------------------------------------------------------------------------
// Kernel A: attention pooling + tail-fused convert(E->bf16).  (R11 version)
// ---------------------------------------------------------------------------
__global__ __launch_bounds__(256) void pool_kernel(
    const int*   __restrict__ log_seqs,
    const float* __restrict__ item_emb,
    const float* __restrict__ attn_key,
    const float* __restrict__ pos_emb,
    float*       __restrict__ Q,
    __bf16*      __restrict__ Qb,
    __bf16*      __restrict__ Eb)
{
    const int b    = blockIdx.x;
    const int t    = threadIdx.x;
    const int wave = t >> 6;
    const int lane = t & 63;

    __shared__ unsigned short s_seq16[L_SEQ][SEQ_ST16];  // 26,400 B
    __shared__ float s_attn[L_SEQ];
    __shared__ float s_red[4];
    __shared__ float s_q[4][DIM];

    // ---- phase 1: seq row -> LDS (bf16), sim[l] ---------------------------
    float sim = -INFINITY;
    if (t < L_SEQ) {
        const int id = log_seqs[(long)b * L_SEQ + t];
        if (id == 0) {
            sim = NEG_BIG;
            const ushort2 z = make_ushort2(0, 0);
            #pragma unroll
            for (int i = 0; i < DIM / 2; ++i)
                *(ushort2*)&s_seq16[t][2 * i] = z;
        } else {
            float acc = 0.f;
            const float4* e4 = (const float4*)(item_emb + (long)id * DIM);
            const float4* p4 = (const float4*)(pos_emb + t * DIM);
            #pragma unroll
            for (int i = 0; i < DIM / 4; ++i) {
                const float4 e = e4[i];
                const float4 p = p4[i];
                float4 f;
                f.x = fmaf(8.f, e.x, p.x);
                f.y = fmaf(8.f, e.y, p.y);
                f.z = fmaf(8.f, e.z, p.z);
                f.w = fmaf(8.f, e.w, p.w);
                const __bf16 h0 = (__bf16)f.x, h1 = (__bf16)f.y;
                const __bf16 h2 = (__bf16)f.z, h3 = (__bf16)f.w;
                ushort2 u0, u1;
                u0.x = __builtin_bit_cast(unsigned short, h0);
                u0.y = __builtin_bit_cast(unsigned short, h1);
                u1.x = __builtin_bit_cast(unsigned short, h2);
                u1.y = __builtin_bit_cast(unsigned short, h3);
                *(ushort2*)&s_seq16[t][4 * i]     = u0;
                *(ushort2*)&s_seq16[t][4 * i + 2] = u1;
                // attn_key reads are thread-uniform -> scalar loads
                acc += f.x * attn_key[4*i+0] + f.y * attn_key[4*i+1]
                     + f.z * attn_key[4*i+2] + f.w * attn_key[4*i+3];
            }
            sim = acc;
        }
    }

    // ---- phase 2: block softmax over l -------------------------------------
    float m = sim;
    #pragma unroll
    for (int off = 32; off > 0; off >>= 1) m = fmaxf(m, __shfl_xor(m, off));
    if (lane == 0) s_red[wave] = m;
    __syncthreads();
    m = fmaxf(fmaxf(s_red[0], s_red[1]), fmaxf(s_red[2], s_red[3]));
    __syncthreads();                             // all waves read s_red

    float p = (t < L_SEQ) ? __expf(sim - m) : 0.f;
    if (t < L_SEQ) s_attn[t] = p;
    float ls = p;
    #pragma unroll
    for (int off = 32; off > 0; off >>= 1) ls += __shfl_xor(ls, off);
    if (lane == 0) s_red[wave] = ls;
    __syncthreads();
    const float inv = 1.0f / (s_red[0] + s_red[1] + s_red[2] + s_red[3]);

    // ---- phase 3: Q accumulation from LDS, L split across waves ------------
    float q = 0.f;
    const int l0 = wave * (L_SEQ / 4);
    #pragma unroll 2
    for (int l = l0; l < l0 + (L_SEQ / 4); ++l) {
        const unsigned int ui = (unsigned int)s_seq16[l][lane] << 16;
        q = fmaf(s_attn[l], __builtin_bit_cast(float, ui), q);
    }
    s_q[wave][lane] = q;
    __syncthreads();

    if (t < DIM) {
        const float qq = (s_q[0][t] + s_q[1][t] + s_q[2][t] + s_q[3][t]) * inv;
        Q[b * DIM + t]  = qq;
        Qb[b * DIM + t] = (__bf16)(qq * LOG2E);  // exp2-domain for logits kernel
    }

    // ---- tail: convert slice of item_emb -> bf16 ---------------------------
    {
        const long n8 = ((long)VOCAB * DIM) / 8;             // 800,008 groups
        for (long g = (long)b * 256 + t; g < n8; g += (long)gridDim.x * 256) {
            const long i = g * 8;
            const float4 f0 = ((const float4*)(item_emb + i))[0];
            const float4 f1 = ((const float4*)(item_emb + i))[1];
            bf16x8 o;
            o[0] = (__bf16)f0.x; o[1] = (__bf16)f0.y; o[2] = (__bf16)f0.z; o[3] = (__bf16)f0.w;
            o[4] = (__bf16)f1.x; o[5] = (__bf16)f1.y; o[6] = (__bf16)f1.z; o[7] = (__bf16)f1.w;
            *(bf16x8*)(Eb + i) = o;
        }
    }
}

// ---------------------------------------------------------------------------
// Kernel B: bf16 MFMA logits GEMM + exp2-sum partials.
// R8 tiling (NC=128, 128 rows/block = 8 b-tiles, waves stride vtiles mod 4,
// 8-MFMA reuse per fragment) + NEW: async global_load_lds prefetch.
// Each wave owns a private 5-slot LDS ring (2 KB/vtile: two 1 KB lane-linear
// fragment planes; dest wave-uniform, src per-lane).  Prologue stages 4
// vtiles; steady state: stage vt+16 -> s_waitcnt vmcnt(8) (4 pairs in
// flight, oldest landed) -> ds_read_b128 x2 -> 16 MFMA + 32 exp2.
// No barriers in the loop.  Overruns land in Eb slack (never consumed);
// 5-deep rotation makes the read-then-rewrite hazard impossible (DMA lands
// >=200cy after issue; ds_read samples <=120cy after an earlier issue).
// XCD-aware decode: XCD k owns chunks == k (mod 8).
// ---------------------------------------------------------------------------
#define NC        128                   // vocab chunks
#define NBG       8                     // batch groups (1024/128)
#define VT_TOTAL  6251                  // ceil(100001/16)
#define VT_FULL   6250
#define VT_PER    49                    // ceil(VT_TOTAL/NC)
#define SLOTS     5
#define SLOT_B    2048                  // bytes per vtile slot

__global__ __launch_bounds__(256) void logits_mfma(
    const __bf16* __restrict__ Eb,      // [VOCAB+slack][64]
    const __bf16* __restrict__ Qb,      // [1024][64], exp2-domain
    float*        __restrict__ partials) // [NC][1024]
{
    const int bid   = blockIdx.x;                 // 0..1023
    const int xcd   = bid & 7;          // HW round-robins blockIdx across XCDs
    const int idx   = bid >> 3;         // 0..127 within this XCD
    const int chunk = xcd + 8 * (idx >> 3);       // chunks == xcd (mod 8)
    const int bg    = idx & 7;
    const int wave  = threadIdx.x >> 6;
    const int lane  = threadIdx.x & 63;
    const int r16   = lane & 15;
    const int hi    = lane >> 4;

    __shared__ char  s_stage[4 * SLOTS * SLOT_B];  // 40,960 B
    __shared__ float s_part[4][128];

    char* wbase = s_stage + wave * (SLOTS * SLOT_B);

    bf16x8 a[8][2];
    #pragma unroll
    for (int t = 0; t < 8; ++t)
        #pragma unroll
        for (int s = 0; s < 2; ++s)
            a[t][s] = *(const bf16x8*)(Qb + ((bg*128 + t*16 + r16) * DIM) + s*32 + hi*8);

    const int vt0    = chunk * VT_PER;
    const int vt_end = min(vt0 + VT_PER, VT_TOTAL);
    int vt = vt0 + wave;

    float ssum[8][4];
    #pragma unroll
    for (int t = 0; t < 8; ++t)
        #pragma unroll
        for (int r = 0; r < 4; ++r) ssum[t][r] = 0.f;

    // per-lane global source for this wave's vtile stream (fragment order)
    const __bf16* src = Eb + ((size_t)vt * 16 + r16) * DIM + hi * 8;

    // stage one vtile: two 1 KB lane-linear planes (dest wave-uniform)
    #define STAGE(slot, sp) do {                                              \
        char* _d = wbase + (slot) * SLOT_B;                                   \
        __builtin_amdgcn_global_load_lds(                                     \
            (const GLB_AS void*)(const void*)(sp),                            \
            (LDS_AS void*)(void*)_d, 16, 0, 0);                               \
        __builtin_amdgcn_global_load_lds(                                     \
            (const GLB_AS void*)(const void*)((sp) + 32),                     \
            (LDS_AS void*)(void*)(_d + 1024), 16, 0, 0);                      \
    } while (0)

    #define DO_TILE(c0, c1, v) do {                                           \
        if ((v) < VT_FULL) {                                                  \
            _Pragma("unroll")                                                 \
            for (int t = 0; t < 8; ++t) {                                     \
                f32x4 acc = {0.f, 0.f, 0.f, 0.f};                             \
                acc = __builtin_amdgcn_mfma_f32_16x16x32_bf16(a[t][0], c0, acc, 0, 0, 0); \
                acc = __builtin_amdgcn_mfma_f32_16x16x32_bf16(a[t][1], c1, acc, 0, 0, 0); \
                _Pragma("unroll")                                             \
                for (int r = 0; r < 4; ++r) ssum[t][r] += fast_exp2(acc[r]);  \
            }                                                                 \
        } else {                                                              \
            const bool valid = ((v) * 16 + r16) < VOCAB;                      \
            _Pragma("unroll")                                                 \
            for (int t = 0; t < 8; ++t) {                                     \
                f32x4 acc = {0.f, 0.f, 0.f, 0.f};                             \
                acc = __builtin_amdgcn_mfma_f32_16x16x32_bf16(a[t][0], c0, acc, 0, 0, 0); \
                acc = __builtin_amdgcn_mfma_f32_16x16x32_bf16(a[t][1], c1, acc, 0, 0, 0); \
                _Pragma("unroll")                                             \
                for (int r = 0; r < 4; ++r) ssum[t][r] += valid ? fast_exp2(acc[r]) : 0.f; \
            }                                                                 \
        }                                                                     \
    } while (0)

    // prologue: stage slots 0..3 <- vt, vt+4, vt+8, vt+12 (4096 elems apart)
    STAGE(0, src);
    STAGE(1, src + 4096);
    STAGE(2, src + 8192);
    STAGE(3, src + 12288);

    int slot_r = 0, slot_w = 4;
    while (vt < vt_end) {
        STAGE(slot_w, src + 16384);               // vt+16 (slack-covered)
        if (++slot_w == SLOTS) slot_w = 0;
        src += 4096;                              // advance 4 vtiles
        asm volatile("s_waitcnt vmcnt(8)" ::: "memory");  // oldest stage landed
        const char* rb = wbase + slot_r * SLOT_B + (size_t)lane * 16;
        const bf16x8 c0 = *(const bf16x8*)rb;
        const bf16x8 c1 = *(const bf16x8*)(rb + 1024);
        if (++slot_r == SLOTS) slot_r = 0;
        DO_TILE(c0, c1, vt);
        vt += 4;
    }
    #undef DO_TILE
    #undef STAGE

    // reduce exp-sums across the 16 vocab cols (lanes differing in bits 0..3)
    #pragma unroll
    for (int t = 0; t < 8; ++t)
        #pragma unroll
        for (int r = 0; r < 4; ++r) {
            float v = ssum[t][r];
            v += __shfl_xor(v, 1);
            v += __shfl_xor(v, 2);
            v += __shfl_xor(v, 4);
            v += __shfl_xor(v, 8);
            ssum[t][r] = v;
        }

    // cross-wave reduce in LDS -> one value per row per block
    if (r16 == 0) {
        #pragma unroll
        for (int t = 0; t < 8; ++t)
            #pragma unroll
            for (int r = 0; r < 4; ++r)
                s_part[wave][t * 16 + hi * 4 + r] = ssum[t][r];
    }
    __syncthreads();

    if (threadIdx.x < 128) {
        const int i = threadIdx.x;
        const float v = s_part[0][i] + s_part[1][i] + s_part[2][i] + s_part[3][i];
        partials[(size_t)chunk * B_TOT + bg * 128 + i] = v;
    }
}

// ---------------------------------------------------------------------------
// Kernel C: reduce partials, exact fp32 pred logit, emit prob.
// ---------------------------------------------------------------------------
__global__ __launch_bounds__(256) void finalize_kernel(
    const float* __restrict__ Q,
    const float* __restrict__ item_emb,
    const int*   __restrict__ pred,
    const float* __restrict__ partials,
    float*       __restrict__ out)
{
    const int b = blockIdx.x * 256 + threadIdx.x;

    float S = 0.f;
    for (int c = 0; c < NC; ++c)
        S += partials[(size_t)c * B_TOT + b];

    const int pv = pred[b];
    float acc = 0.f;
    const float4* e4 = (const float4*)(item_emb + (long)pv * DIM);
    const float4* q4 = (const float4*)(Q + b * DIM);
    #pragma unroll
    for (int i = 0; i < DIM / 4; ++i) {
        const float4 e = e4[i];
        const float4 q = q4[i];
        acc += e.x*q.x + e.y*q.y + e.z*q.z + e.w*q.w;
    }
    out[b] = __expf(acc) / S;
}

// ---------------------------------------------------------------------------
extern "C" void kernel_launch(void* const* d_in, const int* in_sizes, int n_in,
                              void* d_out, int out_size, void* d_ws, size_t ws_size,
                              hipStream_t stream)
{
    const int*   log_seqs = (const int*)  d_in[0];
    const int*   pred     = (const int*)  d_in[1];
    const float* item_emb = (const float*)d_in[2];
    const float* attn_key = (const float*)d_in[3];
    const float* pos_emb  = (const float*)d_in[4];
    float*       out      = (float*)d_out;

    char* ws = (char*)d_ws;
    const size_t eb_bytes = (size_t)(VOCAB + EB_SLACK_ROWS) * DIM * 2;  // + slack
    __bf16* Eb       = (__bf16*)ws;
    __bf16* Qb       = (__bf16*)(ws + eb_bytes);                        // 131,072 B
    float*  Qf       = (float*) (ws + eb_bytes + (size_t)B_TOT * DIM * 2);
    float*  partials = (float*) ((char*)Qf + (size_t)B_TOT * DIM * 4);  // [128][1024] f32

    pool_kernel<<<B_TOT, 256, 0, stream>>>(log_seqs, item_emb, attn_key, pos_emb, Qf, Qb, Eb);
    logits_mfma<<<NBG * NC, 256, 0, stream>>>(Eb, Qb, partials);
    finalize_kernel<<<B_TOT / 256, 256, 0, stream>>>(Qf, item_emb, pred, partials, out);
}